// Round 5
// baseline (236.385 us; speedup 1.0000x reference)
//
#include <hip/hip_runtime.h>
#include <stdint.h>

// y[b,o,w] = relu(bias[o] + sum_{i,kh} W[o,i,kh] * x[b,i,kh,w])
// bf16 MFMA GEMM: M=1024 (o), N=2048 (col=b*32+w), K=16384 (i*16+kh), split-K=8.
// 4 dispatches: prep(topk+zero+convw) -> buildx -> gemm(atomic) -> finalize.

#define NDIM 1024
#define TK   16
#define KDIM 16384   // NDIM*TK
#define NCOL 2048    // 64 batches * 32 width

typedef unsigned short u16;
typedef uint32_t u32;
typedef u16   u16x8  __attribute__((ext_vector_type(8)));
typedef u32   u32x4  __attribute__((ext_vector_type(4)));
typedef __bf16 bf16x8 __attribute__((ext_vector_type(8)));
typedef float  f32x4  __attribute__((ext_vector_type(4)));

__device__ __forceinline__ u16 f2bf(float x) {
    union { float f; unsigned u; } v; v.f = x;
    unsigned r = 0x7FFFu + ((v.u >> 16) & 1u);   // round-to-nearest-even
    return (u16)((v.u + r) >> 16);
}

// async global->LDS, 16B/lane; LDS dest is wave-uniform base + lane*16
__device__ __forceinline__ void load_lds_16B(const u16* g, u16* l) {
    __builtin_amdgcn_global_load_lds(
        (__attribute__((address_space(1))) void*)(uintptr_t)g,
        (__attribute__((address_space(3))) void*)(unsigned)(uintptr_t)l,
        16, 0, 0);
}

// ---------------------------------------------------------------------------
// Kernel 1 (fused, grid-partitioned):
//   blocks [0,256):        exact fp32 top-16 per row (wave/row, registers)
//   blocks [256,2304):     zero d_out (gemm atomically accumulates into it)
//   blocks [2304,10496):   conv_w fp32 -> bf16  (A[o][k], k=i*16+kh)
// ---------------------------------------------------------------------------
#define PREP_TOPK 256
#define PREP_ZERO 2048
#define PREP_CONV 8192

__global__ __launch_bounds__(256) void prep_kernel(const float* __restrict__ f1,
                                                   const float* __restrict__ W,
                                                   int* __restrict__ idx,
                                                   u16* __restrict__ Wb,
                                                   float* __restrict__ out) {
    const int bid = blockIdx.x;
    const int t = threadIdx.x;
    if (bid < PREP_TOPK) {
        // ---- top-16 ----
        const int lane = t & 63;
        const int row  = bid * 4 + (t >> 6);
        float v[16];
        const float* src = f1 + row * NDIM + lane;
        #pragma unroll
        for (int j = 0; j < 16; ++j) v[j] = src[j * 64];
        for (int sel = 0; sel < TK; ++sel) {
            float best = -3.402823466e38f; int bg = 0x7fffffff;
            #pragma unroll
            for (int j = 0; j < 16; ++j)
                if (v[j] > best) { best = v[j]; bg = j * 64 + lane; }
            #pragma unroll
            for (int s = 1; s < 64; s <<= 1) {
                float ov = __shfl_xor(best, s);
                int   og = __shfl_xor(bg, s);
                if (ov > best || (ov == best && og < bg)) { best = ov; bg = og; }
            }
            if (lane == sel) idx[row * TK + sel] = bg;
            #pragma unroll
            for (int j = 0; j < 16; ++j)
                if (bg == j * 64 + lane) v[j] = -3.402823466e38f;
        }
    } else if (bid < PREP_TOPK + PREP_ZERO) {
        // ---- zero the 8MB output accumulator ----
        const int zb = bid - PREP_TOPK;
        f32x4 z = {0.f, 0.f, 0.f, 0.f};
        *(f32x4*)(out + (size_t)(zb * 256 + t) * 4) = z;
    } else {
        // ---- conv_w fp32 -> bf16 ----
        const int tid = (bid - PREP_TOPK - PREP_ZERO) * 256 + t;
        const int base = tid * 8;
        float4 a = *(const float4*)(W + base);
        float4 b = *(const float4*)(W + base + 4);
        u16x8 o;
        o[0] = f2bf(a.x); o[1] = f2bf(a.y); o[2] = f2bf(a.z); o[3] = f2bf(a.w);
        o[4] = f2bf(b.x); o[5] = f2bf(b.y); o[6] = f2bf(b.z); o[7] = f2bf(b.w);
        *(u16x8*)(Wb + base) = o;
    }
}

// ---------------------------------------------------------------------------
// Kernel 2: build Xt[col][k] bf16, col=b*32+w, k=i*16+kh.
// Thread (ci,khp,wq): 4 coalesced float4 reads (kh and kh+1 rows), packs
// bf16 pairs -> 8x ds_write_b32 with col^(w&24) swizzle (2-way = free);
// read side: 2x ds_read_b128 at XORed seg -> coalesced 32B global stores.
// ---------------------------------------------------------------------------
__global__ __launch_bounds__(256) void buildx_kernel(const float* __restrict__ f1,
                                                     const int* __restrict__ idx,
                                                     u16* __restrict__ Xt) {
    __shared__ u32 Ls[32 * 64];             // [w][(ci*8+khp) ^ (w&24)], 8KB
    const int b  = blockIdx.x >> 7;         // grid 64*128
    const int i8 = blockIdx.x & 127;
    const int t  = threadIdx.x;
    const int ci  = t >> 5;                 // 0..7: which i
    const int s   = t & 31;
    const int khp = s >> 2;                 // 0..7: kh pair (2*khp, 2*khp+1)
    const int wq  = s & 3;                  // 0..3: w block of 8
    const int i  = i8 * 8 + ci;
    const int q = i & 3, nl = i >> 6, tt = (i >> 2) & 15;
    const int row = (q < 2) ? (b * 16 + nl) : idx[(b * 16 + nl) * TK + tt];
    const float* src = f1 + row * NDIM + (q & 1) * 512;
    const int base0 = khp * 64 + wq * 8;    // kh=2*khp row, w=wq*8
    float4 a0 = *(const float4*)(src + base0);
    float4 a1 = *(const float4*)(src + base0 + 4);
    float4 b0 = *(const float4*)(src + base0 + 32);   // kh+1 row
    float4 b1 = *(const float4*)(src + base0 + 36);
    float lo[8] = {a0.x, a0.y, a0.z, a0.w, a1.x, a1.y, a1.z, a1.w};
    float hi[8] = {b0.x, b0.y, b0.z, b0.w, b1.x, b1.y, b1.z, b1.w};
    const int colsw = (ci * 8 + khp) ^ (wq << 3);     // w&24 == wq<<3
    #pragma unroll
    for (int j = 0; j < 8; ++j) {
        const int w = wq * 8 + j;
        u32 p = (u32)f2bf(lo[j]) | ((u32)f2bf(hi[j]) << 16);
        Ls[w * 64 + colsw] = p;
    }
    __syncthreads();
    const int wv = t >> 3, seg = t & 7;     // output row wv, k-chunk seg*16
    const int swz = wv & 24;                // XOR key (bits 3-4 of col)
    u32x4 r0 = *(const u32x4*)(Ls + wv * 64 + ((seg * 8 + 0) ^ swz));
    u32x4 r1 = *(const u32x4*)(Ls + wv * 64 + ((seg * 8 + 4) ^ swz));
    u16* dst = Xt + (size_t)(b * 32 + wv) * KDIM + i8 * 128 + seg * 16;
    *(u32x4*)(dst)     = r0;   // k = seg*16 + 0..7
    *(u32x4*)(dst + 8) = r1;   // k = seg*16 + 8..15
}

// ---------------------------------------------------------------------------
// Kernel 3: bf16 MFMA GEMM, 128x128 tile, BK=64, split-K=8: grid 1024
// blocks x 256 thr = 4 blocks/CU (4 independent barrier domains/CU to
// overlap the vmcnt(0)+s_barrier drain). XCD-aware flat order: f=m*128+u,
// u=(z,n); blocks sharing a B panel (same u) land on XCD u%8.
// XOR-swizzled LDS (swizzle on the GLOBAL source chunk). Atomic epilogue.
// ---------------------------------------------------------------------------
#define BM 128
#define BN 128
#define BK 64
#define ZSPLIT 8
#define KCH (KDIM / ZSPLIT)   // 2048 per split

__global__ __launch_bounds__(256, 4) void gemm_kernel(const u16* __restrict__ A,
                                                      const u16* __restrict__ B,
                                                      float* __restrict__ out) {
    __shared__ __align__(16) u16 As[BM * BK];   // 16KB, [row][chunk^(row&7)]
    __shared__ __align__(16) u16 Bs[BN * BK];   // 16KB
    const int f = blockIdx.x;            // 0..1023
    const int m = f >> 7;                // 0..7
    const int u = f & 127;               // (z,n) group -> XCD u%8
    const int n = u & 15;
    const int z = u >> 4;
    const int t    = threadIdx.x;
    const int lane = t & 63;
    const int wave = t >> 6;
    const int wm   = (wave >> 1) * 64;
    const int wn   = (wave & 1) * 64;
    const int quad = lane >> 4;
    const int l16  = lane & 15;
    const int sw   = l16 & 7;            // == row&7 for all fragment rows
    const int o0 = m * BM;
    const int n0 = n * BN;
    const int kb = z * KCH;

    f32x4 acc[4][4] = {};

    // staging: slot (row=32c+rA, chunk c8) holds global chunk c8^(rA&7)
    const int rA = t >> 3;               // 0..31
    const int c8 = t & 7;
    const int csw = (c8 ^ (rA & 7)) * 8;
    const u16* gA = A + (size_t)(o0 + rA) * KDIM + kb + csw;
    const u16* gB = B + (size_t)(n0 + rA) * KDIM + kb + csw;
    u16* lA = As + t * 8;
    u16* lB = Bs + t * 8;

    for (int k0 = 0; k0 < KCH; k0 += BK) {
        #pragma unroll
        for (int c = 0; c < 4; ++c) {
            load_lds_16B(gA + (size_t)c * 32 * KDIM + k0, lA + c * 2048);
            load_lds_16B(gB + (size_t)c * 32 * KDIM + k0, lB + c * 2048);
        }
        __syncthreads();

        #pragma unroll
        for (int ks = 0; ks < 2; ++ks) {
            bf16x8 af[4], bfr[4];
            #pragma unroll
            for (int mt = 0; mt < 4; ++mt) {
                u16x8 bits = *(const u16x8*)(As + (wm + mt * 16 + l16) * BK
                                                + (((ks * 4 + quad) ^ sw) * 8));
                af[mt] = __builtin_bit_cast(bf16x8, bits);
            }
            #pragma unroll
            for (int nt = 0; nt < 4; ++nt) {
                u16x8 bits = *(const u16x8*)(Bs + (wn + nt * 16 + l16) * BK
                                                + (((ks * 4 + quad) ^ sw) * 8));
                bfr[nt] = __builtin_bit_cast(bf16x8, bits);
            }
            #pragma unroll
            for (int mt = 0; mt < 4; ++mt)
                #pragma unroll
                for (int nt = 0; nt < 4; ++nt)
                    acc[mt][nt] = __builtin_amdgcn_mfma_f32_16x16x32_bf16(
                        af[mt], bfr[nt], acc[mt][nt], 0, 0, 0);
        }
        __syncthreads();
    }

    // epilogue: C/D row=quad*4+reg, col=l16; atomic-accumulate at final
    // scattered position: out[(b*16+(o>>6))*2048 + (o&63)*32 + w]
    #pragma unroll
    for (int nt = 0; nt < 4; ++nt) {
        const int nn = n0 + wn + nt * 16 + l16;
        const int bb = nn >> 5, w = nn & 31;
        #pragma unroll
        for (int mt = 0; mt < 4; ++mt) {
            #pragma unroll
            for (int r = 0; r < 4; ++r) {
                const int o = o0 + wm + mt * 16 + quad * 4 + r;
                unsafeAtomicAdd(out + (size_t)(bb * 16 + (o >> 6)) * 2048
                                    + (o & 63) * 32 + w,
                                acc[mt][nt][r]);
            }
        }
    }
}

// ---------------------------------------------------------------------------
// Kernel 4: in-place bias + relu on the accumulated output.
// ---------------------------------------------------------------------------
__global__ __launch_bounds__(256) void finalize_kernel(float* __restrict__ out,
                                                       const float* __restrict__ bias) {
    const int tid = blockIdx.x * 256 + threadIdx.x;
    const int f = tid * 4;
    const int o = ((f >> 11) & 15) * 64 + ((f & 2047) >> 5);
    const float bv = bias[o];
    float4 x = *(float4*)(out + f);
    x.x = fmaxf(x.x + bv, 0.f);
    x.y = fmaxf(x.y + bv, 0.f);
    x.z = fmaxf(x.z + bv, 0.f);
    x.w = fmaxf(x.w + bv, 0.f);
    *(float4*)(out + f) = x;
}

// ---------------------------------------------------------------------------
extern "C" void kernel_launch(void* const* d_in, const int* in_sizes, int n_in,
                              void* d_out, int out_size, void* d_ws, size_t ws_size,
                              hipStream_t stream) {
    const float* f1   = (const float*)d_in[0];   // [1024][1024]
    const float* Wc   = (const float*)d_in[1];   // [1024][1024][16][1]
    const float* bias = (const float*)d_in[2];   // [1024]
    float* out = (float*)d_out;                  // [1024][2048]

    // workspace: idx (64KB) | Wb bf16 (32MB) | Xt bf16 (64MB)  ~= 96MB
    int* idx = (int*)d_ws;
    u16* Wb  = (u16*)((char*)d_ws + 65536);
    u16* Xt  = (u16*)((char*)d_ws + 65536 + (size_t)NDIM * KDIM * 2);

    prep_kernel<<<PREP_TOPK + PREP_ZERO + PREP_CONV, 256, 0, stream>>>(f1, Wc, idx, Wb, out);
    buildx_kernel<<<64 * 128, 256, 0, stream>>>(f1, idx, Xt);
    gemm_kernel<<<1024, 256, 0, stream>>>(Wb, Xt, out);
    finalize_kernel<<<(NDIM * NCOL) / (4 * 256), 256, 0, stream>>>(out, bias);
}

// Round 6
// 180.106 us; speedup vs baseline: 1.3125x; 1.3125x over previous
//
#include <hip/hip_runtime.h>
#include <stdint.h>

// y[b,o,w] = relu(bias[o] + sum_{i,kh} W[o,i,kh] * x[b,i,kh,w])
// q=i&3 split: q<2 ("rep") has x independent of tt=(i>>2)&15 -> pre-sum W over
// tt => K=512 GEMM. q>=2 ("pos") keeps the gathered K=8192 GEMM.
// 4 dispatches: prep(topk+zero+convw_pos+W1) -> buildx(Xt_pos+B1) ->
//               gemm(pos 512 blk + rep 128 blk, atomic) -> finalize.

#define NDIM 1024
#define TK   16
#define KPOS 8192    // pos K: 512 i's * 16 kh
#define KREP 512     // rep K: 32 (nl,q) * 16 kh
#define NCOL 2048    // 64 batches * 32 width

typedef unsigned short u16;
typedef uint32_t u32;
typedef u16   u16x8  __attribute__((ext_vector_type(8)));
typedef u32   u32x4  __attribute__((ext_vector_type(4)));
typedef __bf16 bf16x8 __attribute__((ext_vector_type(8)));
typedef float  f32x4  __attribute__((ext_vector_type(4)));

__device__ __forceinline__ u16 f2bf(float x) {
    union { float f; unsigned u; } v; v.f = x;
    unsigned r = 0x7FFFu + ((v.u >> 16) & 1u);   // round-to-nearest-even
    return (u16)((v.u + r) >> 16);
}

// async global->LDS, 16B/lane; LDS dest is wave-uniform base + lane*16
__device__ __forceinline__ void load_lds_16B(const u16* g, u16* l) {
    __builtin_amdgcn_global_load_lds(
        (__attribute__((address_space(1))) void*)(uintptr_t)g,
        (__attribute__((address_space(3))) void*)(unsigned)(uintptr_t)l,
        16, 0, 0);
}

// ---------------------------------------------------------------------------
// Kernel 1 (fused, grid-partitioned):
//   [0,256):      top-16 per row (wave/row, registers, exact fp32)
//   [256,2304):   zero d_out (gemm atomically accumulates into it)
//   [2304,6400):  conv_w (q>=2 half) fp32 -> bf16 A_pos[o][k'], k'=i'*16+kh,
//                 i' = nl*32+tt*2+qp,  i = nl*64+tt*4+qp+2
//   [6400,7424):  W1[o][kr] = bf16(sum_tt W[o, nl*64+tt*4+q, kh]),
//                 kr = (nl*2+q)*16+kh, q in {0,1}
// ---------------------------------------------------------------------------
#define PREP_TOPK 256
#define PREP_ZERO 2048
#define PREP_CONV 4096
#define PREP_W1   1024

__global__ __launch_bounds__(256) void prep_kernel(const float* __restrict__ f1,
                                                   const float* __restrict__ W,
                                                   int* __restrict__ idx,
                                                   u16* __restrict__ Wb,
                                                   u16* __restrict__ W1b,
                                                   float* __restrict__ out) {
    const int bid = blockIdx.x;
    const int t = threadIdx.x;
    if (bid < PREP_TOPK) {
        // ---- top-16 ----
        const int lane = t & 63;
        const int row  = bid * 4 + (t >> 6);
        float v[16];
        const float* src = f1 + row * NDIM + lane;
        #pragma unroll
        for (int j = 0; j < 16; ++j) v[j] = src[j * 64];
        for (int sel = 0; sel < TK; ++sel) {
            float best = -3.402823466e38f; int bg = 0x7fffffff;
            #pragma unroll
            for (int j = 0; j < 16; ++j)
                if (v[j] > best) { best = v[j]; bg = j * 64 + lane; }
            #pragma unroll
            for (int s = 1; s < 64; s <<= 1) {
                float ov = __shfl_xor(best, s);
                int   og = __shfl_xor(bg, s);
                if (ov > best || (ov == best && og < bg)) { best = ov; bg = og; }
            }
            if (lane == sel) idx[row * TK + sel] = bg;
            #pragma unroll
            for (int j = 0; j < 16; ++j)
                if (bg == j * 64 + lane) v[j] = -3.402823466e38f;
        }
    } else if (bid < PREP_TOPK + PREP_ZERO) {
        // ---- zero the 8MB output accumulator ----
        const int zb = bid - PREP_TOPK;
        f32x4 z = {0.f, 0.f, 0.f, 0.f};
        *(f32x4*)(out + (size_t)(zb * 256 + t) * 4) = z;
    } else if (bid < PREP_TOPK + PREP_ZERO + PREP_CONV) {
        // ---- conv_w pos half -> bf16 ----
        const int tid = (bid - PREP_TOPK - PREP_ZERO) * 256 + t;  // < 1048576
        const int o  = tid >> 10;
        const int r  = tid & 1023;
        const int kp0 = r * 8;                 // k' base (8 consecutive)
        const int ip  = r >> 1;                // i' = kp0>>4
        const int kh0 = (r & 1) * 8;
        const int i = (ip >> 5) * 64 + ((ip >> 1) & 15) * 4 + (ip & 1) + 2;
        const float* src = W + (size_t)o * 16384 + i * 16 + kh0;
        float4 a = *(const float4*)(src);
        float4 b = *(const float4*)(src + 4);
        u16x8 ov;
        ov[0] = f2bf(a.x); ov[1] = f2bf(a.y); ov[2] = f2bf(a.z); ov[3] = f2bf(a.w);
        ov[4] = f2bf(b.x); ov[5] = f2bf(b.y); ov[6] = f2bf(b.z); ov[7] = f2bf(b.w);
        *(u16x8*)(Wb + (size_t)o * KPOS + kp0) = ov;
    } else {
        // ---- W1 reduction over tt (rep half) ----
        const int o = bid - PREP_TOPK - PREP_ZERO - PREP_CONV;   // 0..1023
        const float* wrow = W + (size_t)o * 16384;
        #pragma unroll
        for (int h = 0; h < 2; ++h) {
            const int kr = h * 256 + t;        // 0..511
            const int nl = kr >> 5, q = (kr >> 4) & 1, kh = kr & 15;
            const float* base = wrow + (nl * 64 + q) * 16 + kh;
            float s = 0.f;
            #pragma unroll
            for (int tt = 0; tt < 16; ++tt) s += base[tt * 64];
            W1b[o * KREP + kr] = f2bf(s);
        }
    }
}

// ---------------------------------------------------------------------------
// Kernel 2 (fused): LDS-transpose builders.
//   [0,4096):     Xt_pos[col][k'] = bf16(f1[idx[b*16+nl][tt], qp*512+kh*32+w])
//   [4096,4352):  B1[col][kr]     = bf16(f1[b*16+nl,  q*512+kh*32+w])
// Thread (ci,khp,wq): 4 coalesced float4 reads (kh, kh+1 rows), packs bf16
// pairs -> 8x ds_write_b32 with col^(w&24) swizzle; reads 2x ds_read_b128.
// ---------------------------------------------------------------------------
__global__ __launch_bounds__(256) void buildx_kernel(const float* __restrict__ f1,
                                                     const int* __restrict__ idx,
                                                     u16* __restrict__ Xt,
                                                     u16* __restrict__ B1) {
    __shared__ u32 Ls[32 * 64];             // [w][(ci*8+khp) ^ (w&24)], 8KB
    const int bid = blockIdx.x;
    const int t  = threadIdx.x;
    const int ci  = t >> 5;                 // 0..7: which i within group
    const int s   = t & 31;
    const int khp = s >> 2;                 // 0..7: kh pair (2*khp, 2*khp+1)
    const int wq  = s & 3;                  // 0..3: w block of 8
    int b, i8, row, qoff, ostride;
    u16* dstbase;
    if (bid < 4096) {
        b = bid >> 6; i8 = bid & 63;
        const int ip = i8 * 8 + ci;         // 0..511
        const int nl = ip >> 5, tt = (ip >> 1) & 15, qp = ip & 1;
        row = idx[(b * 16 + nl) * TK + tt];
        qoff = qp * 512;
        dstbase = Xt; ostride = KPOS;
    } else {
        const int rb = bid - 4096;          // 0..255
        b = rb >> 2; i8 = rb & 3;
        const int iq = i8 * 8 + ci;         // 0..31 = nl*2+q
        row = b * 16 + (iq >> 1);
        qoff = (iq & 1) * 512;
        dstbase = B1; ostride = KREP;
    }
    const float* src = f1 + row * NDIM + qoff;
    const int base0 = khp * 64 + wq * 8;    // kh=2*khp row, w=wq*8
    float4 a0 = *(const float4*)(src + base0);
    float4 a1 = *(const float4*)(src + base0 + 4);
    float4 b0 = *(const float4*)(src + base0 + 32);   // kh+1 row
    float4 b1 = *(const float4*)(src + base0 + 36);
    float lo[8] = {a0.x, a0.y, a0.z, a0.w, a1.x, a1.y, a1.z, a1.w};
    float hi[8] = {b0.x, b0.y, b0.z, b0.w, b1.x, b1.y, b1.z, b1.w};
    const int colsw = (ci * 8 + khp) ^ (wq << 3);     // w&24 == wq<<3
    #pragma unroll
    for (int j = 0; j < 8; ++j) {
        const int w = wq * 8 + j;
        u32 p = (u32)f2bf(lo[j]) | ((u32)f2bf(hi[j]) << 16);
        Ls[w * 64 + colsw] = p;
    }
    __syncthreads();
    const int wv = t >> 3, seg = t & 7;     // output row wv, k-chunk seg*16
    const int swz = wv & 24;                // XOR key (bits 3-4 of col)
    u32x4 r0 = *(const u32x4*)(Ls + wv * 64 + ((seg * 8 + 0) ^ swz));
    u32x4 r1 = *(const u32x4*)(Ls + wv * 64 + ((seg * 8 + 4) ^ swz));
    u16* dst = dstbase + (size_t)(b * 32 + wv) * ostride + i8 * 128 + seg * 16;
    *(u32x4*)(dst)     = r0;   // k = seg*16 + 0..7
    *(u32x4*)(dst + 8) = r1;   // k = seg*16 + 8..15
}

// ---------------------------------------------------------------------------
// Kernel 3: bf16 MFMA GEMM, 128x128 tile, BK=64. Grid partition:
//   f < 512:  pos GEMM K=8192, split-K=4 (f=m*64+u, u=(n,z); XCD = u%8 so
//             blocks sharing a B panel share an XCD L2)
//   f >= 512: rep GEMM K=512 (128 blocks)
// XOR-swizzled LDS (swizzle on the GLOBAL source chunk). Atomic epilogue.
// ---------------------------------------------------------------------------
#define BM 128
#define BN 128
#define BK 64

__global__ __launch_bounds__(256, 2) void gemm_kernel(const u16* __restrict__ Ap,
                                                      const u16* __restrict__ Bp,
                                                      const u16* __restrict__ A1,
                                                      const u16* __restrict__ B1,
                                                      float* __restrict__ out) {
    __shared__ __align__(16) u16 As[BM * BK];   // 16KB, [row][chunk^(row&7)]
    __shared__ __align__(16) u16 Bs[BN * BK];   // 16KB
    const int f = blockIdx.x;            // 0..639
    int m, n, kb, kiters, stride;
    const u16 *Ab, *Bb;
    if (f < 512) {
        m = f >> 6; const int u = f & 63; n = u & 15;
        stride = KPOS; kb = (u >> 4) * 2048; kiters = 32; Ab = Ap; Bb = Bp;
    } else {
        const int g = f - 512; m = g >> 4; n = g & 15;
        stride = KREP; kb = 0; kiters = 8; Ab = A1; Bb = B1;
    }
    const int t    = threadIdx.x;
    const int lane = t & 63;
    const int wave = t >> 6;
    const int wm   = (wave >> 1) * 64;
    const int wn   = (wave & 1) * 64;
    const int quad = lane >> 4;
    const int l16  = lane & 15;
    const int sw   = l16 & 7;            // == row&7 for all fragment rows
    const int o0 = m * BM;
    const int n0 = n * BN;

    f32x4 acc[4][4] = {};

    // staging: slot (row=32c+rA, chunk c8) holds global chunk c8^(rA&7)
    const int rA = t >> 3;               // 0..31
    const int c8 = t & 7;
    const int csw = (c8 ^ (rA & 7)) * 8;
    const u16* gA = Ab + (size_t)(o0 + rA) * stride + kb + csw;
    const u16* gB = Bb + (size_t)(n0 + rA) * stride + kb + csw;
    u16* lA = As + t * 8;
    u16* lB = Bs + t * 8;

    for (int it = 0; it < kiters; ++it) {
        const int k0 = it * BK;
        #pragma unroll
        for (int c = 0; c < 4; ++c) {
            load_lds_16B(gA + (size_t)(c * 32) * stride + k0, lA + c * 2048);
            load_lds_16B(gB + (size_t)(c * 32) * stride + k0, lB + c * 2048);
        }
        __syncthreads();

        #pragma unroll
        for (int ks = 0; ks < 2; ++ks) {
            bf16x8 af[4], bfr[4];
            #pragma unroll
            for (int mt = 0; mt < 4; ++mt) {
                u16x8 bits = *(const u16x8*)(As + (wm + mt * 16 + l16) * BK
                                                + (((ks * 4 + quad) ^ sw) * 8));
                af[mt] = __builtin_bit_cast(bf16x8, bits);
            }
            #pragma unroll
            for (int nt = 0; nt < 4; ++nt) {
                u16x8 bits = *(const u16x8*)(Bs + (wn + nt * 16 + l16) * BK
                                                + (((ks * 4 + quad) ^ sw) * 8));
                bfr[nt] = __builtin_bit_cast(bf16x8, bits);
            }
            #pragma unroll
            for (int mt = 0; mt < 4; ++mt)
                #pragma unroll
                for (int nt = 0; nt < 4; ++nt)
                    acc[mt][nt] = __builtin_amdgcn_mfma_f32_16x16x32_bf16(
                        af[mt], bfr[nt], acc[mt][nt], 0, 0, 0);
        }
        __syncthreads();
    }

    // epilogue: C/D row=quad*4+reg, col=l16; atomic-accumulate at final
    // scattered position: out[(b*16+(o>>6))*2048 + (o&63)*32 + w]
    #pragma unroll
    for (int nt = 0; nt < 4; ++nt) {
        const int nn = n0 + wn + nt * 16 + l16;
        const int bb = nn >> 5, w = nn & 31;
        #pragma unroll
        for (int mt = 0; mt < 4; ++mt) {
            #pragma unroll
            for (int r = 0; r < 4; ++r) {
                const int o = o0 + wm + mt * 16 + quad * 4 + r;
                unsafeAtomicAdd(out + (size_t)(bb * 16 + (o >> 6)) * 2048
                                    + (o & 63) * 32 + w,
                                acc[mt][nt][r]);
            }
        }
    }
}

// ---------------------------------------------------------------------------
// Kernel 4: in-place bias + relu on the accumulated output.
// ---------------------------------------------------------------------------
__global__ __launch_bounds__(256) void finalize_kernel(float* __restrict__ out,
                                                       const float* __restrict__ bias) {
    const int tid = blockIdx.x * 256 + threadIdx.x;
    const int f = tid * 4;
    const int o = ((f >> 11) & 15) * 64 + ((f & 2047) >> 5);
    const float bv = bias[o];
    float4 x = *(float4*)(out + f);
    x.x = fmaxf(x.x + bv, 0.f);
    x.y = fmaxf(x.y + bv, 0.f);
    x.z = fmaxf(x.z + bv, 0.f);
    x.w = fmaxf(x.w + bv, 0.f);
    *(float4*)(out + f) = x;
}

// ---------------------------------------------------------------------------
extern "C" void kernel_launch(void* const* d_in, const int* in_sizes, int n_in,
                              void* d_out, int out_size, void* d_ws, size_t ws_size,
                              hipStream_t stream) {
    const float* f1   = (const float*)d_in[0];   // [1024][1024]
    const float* Wc   = (const float*)d_in[1];   // [1024][1024][16][1]
    const float* bias = (const float*)d_in[2];   // [1024]
    float* out = (float*)d_out;                  // [1024][2048]

    // workspace layout (bytes):
    //   idx:    0        (64KB)
    //   Wb_pos: 65536    (1024*8192*2  = 16MB)
    //   Xt_pos: 16842752 (2048*8192*2  = 32MB)
    //   W1b:    50397184 (1024*512*2   = 1MB)
    //   B1:     51445760 (2048*512*2   = 2MB)
    int* idx = (int*)d_ws;
    u16* Wb  = (u16*)((char*)d_ws + 65536);
    u16* Xt  = (u16*)((char*)d_ws + 16842752);
    u16* W1b = (u16*)((char*)d_ws + 50397184);
    u16* B1  = (u16*)((char*)d_ws + 51445760);

    prep_kernel<<<PREP_TOPK + PREP_ZERO + PREP_CONV + PREP_W1, 256, 0, stream>>>(
        f1, Wc, idx, Wb, W1b, out);
    buildx_kernel<<<4096 + 256, 256, 0, stream>>>(f1, idx, Xt, B1);
    gemm_kernel<<<512 + 128, 256, 0, stream>>>(Wb, Xt, W1b, B1, out);
    finalize_kernel<<<(NDIM * NCOL) / (4 * 256), 256, 0, stream>>>(out, bias);
}

// Round 7
// 173.875 us; speedup vs baseline: 1.3595x; 1.0358x over previous
//
#include <hip/hip_runtime.h>
#include <stdint.h>

// y[b,o,w] = relu(bias[o] + sum_{i,kh} W[o,i,kh] * x[b,i,kh,w])
// q=i&3 split: q<2 ("rep") -> pre-sum W over tt => K=512 GEMM; q>=2 ("pos")
// keeps the gathered K=8192 GEMM. The gather is fused INTO the GEMM staging:
// f1 is pre-transposed to f1t[row][q][w][kh] bf16 (2MB, L2-resident), so each
// B-tile chunk (b,i') is one contiguous 1KB global_load_lds call.
// 3 dispatches: prep(topk+zero+convw_pos+W1+f1t) -> gemm -> finalize.

#define NDIM 1024
#define TK   16
#define KPOS 8192    // pos K: 512 i's * 16 kh
#define KREP 512     // rep K: 32 (nl,q) * 16 kh
#define NCOL 2048    // 64 batches * 32 width

typedef unsigned short u16;
typedef uint32_t u32;
typedef u16   u16x8  __attribute__((ext_vector_type(8)));
typedef __bf16 bf16x8 __attribute__((ext_vector_type(8)));
typedef float  f32x4  __attribute__((ext_vector_type(4)));

__device__ __forceinline__ u16 f2bf(float x) {
    union { float f; unsigned u; } v; v.f = x;
    unsigned r = 0x7FFFu + ((v.u >> 16) & 1u);   // round-to-nearest-even
    return (u16)((v.u + r) >> 16);
}

// async global->LDS, 16B/lane; LDS dest is wave-uniform base + lane*16
__device__ __forceinline__ void load_lds_16B(const u16* g, u16* l) {
    __builtin_amdgcn_global_load_lds(
        (__attribute__((address_space(1))) void*)(uintptr_t)g,
        (__attribute__((address_space(3))) void*)(unsigned)(uintptr_t)l,
        16, 0, 0);
}

// ---------------------------------------------------------------------------
// Kernel 1 (fused, grid-partitioned):
//   [0,256):      top-16 per row (wave/row, registers, exact fp32)
//   [256,2304):   zero d_out
//   [2304,6400):  conv_w pos half fp32 -> bf16 A_pos[o][k'], k'=i'*16+kh
//   [6400,7424):  W1[o][kr] = bf16(sum_tt W[o, nl*64+tt*4+q, kh]), q in {0,1}
//   [7424,7680):  f1t[row][q][w][kh^swp] = bf16(f1[row, q*512+kh*32+w]),
//                 swp = 8*((w>>2)&1)  (bank-spread half-swap for GEMM reads)
// ---------------------------------------------------------------------------
#define PREP_TOPK 256
#define PREP_ZERO 2048
#define PREP_CONV 4096
#define PREP_W1   1024
#define PREP_F1T  256

__global__ __launch_bounds__(256) void prep_kernel(const float* __restrict__ f1,
                                                   const float* __restrict__ W,
                                                   int* __restrict__ idx,
                                                   u16* __restrict__ Wb,
                                                   u16* __restrict__ W1b,
                                                   u16* __restrict__ f1t,
                                                   float* __restrict__ out) {
    const int bid = blockIdx.x;
    const int t = threadIdx.x;
    if (bid < PREP_TOPK) {
        // ---- top-16 ----
        const int lane = t & 63;
        const int row  = bid * 4 + (t >> 6);
        float v[16];
        const float* src = f1 + row * NDIM + lane;
        #pragma unroll
        for (int j = 0; j < 16; ++j) v[j] = src[j * 64];
        for (int sel = 0; sel < TK; ++sel) {
            float best = -3.402823466e38f; int bg = 0x7fffffff;
            #pragma unroll
            for (int j = 0; j < 16; ++j)
                if (v[j] > best) { best = v[j]; bg = j * 64 + lane; }
            #pragma unroll
            for (int s = 1; s < 64; s <<= 1) {
                float ov = __shfl_xor(best, s);
                int   og = __shfl_xor(bg, s);
                if (ov > best || (ov == best && og < bg)) { best = ov; bg = og; }
            }
            if (lane == sel) idx[row * TK + sel] = bg;
            #pragma unroll
            for (int j = 0; j < 16; ++j)
                if (bg == j * 64 + lane) v[j] = -3.402823466e38f;
        }
    } else if (bid < PREP_TOPK + PREP_ZERO) {
        // ---- zero the 8MB output accumulator ----
        const int zb = bid - PREP_TOPK;
        f32x4 z = {0.f, 0.f, 0.f, 0.f};
        *(f32x4*)(out + (size_t)(zb * 256 + t) * 4) = z;
    } else if (bid < PREP_TOPK + PREP_ZERO + PREP_CONV) {
        // ---- conv_w pos half -> bf16: i' = nl*32+tt*2+qp, i = nl*64+tt*4+qp+2
        const int tid = (bid - PREP_TOPK - PREP_ZERO) * 256 + t;  // < 1048576
        const int o  = tid >> 10;
        const int r  = tid & 1023;
        const int kp0 = r * 8;                 // k' base (8 consecutive)
        const int ip  = r >> 1;                // i'
        const int kh0 = (r & 1) * 8;
        const int i = (ip >> 5) * 64 + ((ip >> 1) & 15) * 4 + (ip & 1) + 2;
        const float* src = W + (size_t)o * 16384 + i * 16 + kh0;
        float4 a = *(const float4*)(src);
        float4 b = *(const float4*)(src + 4);
        u16x8 ov;
        ov[0] = f2bf(a.x); ov[1] = f2bf(a.y); ov[2] = f2bf(a.z); ov[3] = f2bf(a.w);
        ov[4] = f2bf(b.x); ov[5] = f2bf(b.y); ov[6] = f2bf(b.z); ov[7] = f2bf(b.w);
        *(u16x8*)(Wb + (size_t)o * KPOS + kp0) = ov;
    } else if (bid < PREP_TOPK + PREP_ZERO + PREP_CONV + PREP_W1) {
        // ---- W1 reduction over tt (rep half) ----
        const int o = bid - PREP_TOPK - PREP_ZERO - PREP_CONV;   // 0..1023
        const float* wrow = W + (size_t)o * 16384;
        #pragma unroll
        for (int h = 0; h < 2; ++h) {
            const int kr = h * 256 + t;        // 0..511
            const int nl = kr >> 5, q = (kr >> 4) & 1, kh = kr & 15;
            const float* base = wrow + (nl * 64 + q) * 16 + kh;
            float s = 0.f;
            #pragma unroll
            for (int tt = 0; tt < 16; ++tt) s += base[tt * 64];
            W1b[o * KREP + kr] = f2bf(s);
        }
    } else {
        // ---- f1 -> f1t bf16 transpose (w-major, kh half-swapped by w>>2&1) ----
        const int gb = bid - PREP_TOPK - PREP_ZERO - PREP_CONV - PREP_W1; // 0..255
        const int unit = t >> 5;               // 0..7
        const int w = t & 31;
        const int rq = gb * 8 + unit;          // 0..2047
        const int row = rq >> 1, q = rq & 1;
        const float* src = f1 + row * NDIM + q * 512;
        const int swp = ((w >> 2) & 1) * 8;
        u16 tmp[16];
        #pragma unroll
        for (int kh = 0; kh < 16; ++kh)
            tmp[kh ^ swp] = f2bf(src[kh * 32 + w]);   // coalesced per-kh across lanes
        u16* dst = f1t + ((size_t)row * 2 + q) * 512 + w * 16;
        *(u16x8*)(dst)     = *(u16x8*)(tmp);
        *(u16x8*)(dst + 8) = *(u16x8*)(tmp + 8);
    }
}

// ---------------------------------------------------------------------------
// Kernel 2: bf16 MFMA GEMM, 128x128 tile, BK=64, B gathered inline from f1t.
//   f < 512:  pos GEMM K=8192, split-K=4 (f=m*64+u, u=(n,z); XCD = u%8)
//   f >= 512: rep GEMM K=512 (128 blocks)
// A: global_load_lds from Wb/W1b with row&7 chunk XOR swizzle (as r6).
// B: per-wave DMA — wave ci stages 4 chunks (bloc 0..3), each one contiguous
//    1KB run of f1t[row][qp] (row from idx for pos, arithmetic for rep).
//    LDS layout Bs[ci][bloc][w][half] (DMA-forced); fragment reads are
//    ds_read_b128 with the kh-half swap keyed on (w>>2)&1 -> 2-way = free.
// Epilogue: scatter-atomic into zeroed out.
// ---------------------------------------------------------------------------
#define BM 128
#define BN 128
#define BK 64

__global__ __launch_bounds__(256, 2) void gemm_kernel(const u16* __restrict__ Ap,
                                                      const u16* __restrict__ A1,
                                                      const u16* __restrict__ f1t,
                                                      const int* __restrict__ idx,
                                                      float* __restrict__ out) {
    __shared__ __align__(16) u16 As[BM * BK];   // 16KB, [row][chunk^(row&7)]
    __shared__ __align__(16) u16 Bs[16 * 512];  // 16KB, [ci][bloc][w][half]
    const int f = blockIdx.x;            // 0..639
    int m, n, kb, kiters, astride;
    const u16* Ab;
    bool isPos;
    if (f < 512) {
        m = f >> 6; const int u = f & 63; n = u & 15;
        astride = KPOS; kb = (u >> 4) * 2048; kiters = 32; Ab = Ap; isPos = true;
    } else {
        const int g = f - 512; m = g >> 4; n = g & 15;
        astride = KREP; kb = 0; kiters = 8; Ab = A1; isPos = false;
    }
    const int t    = threadIdx.x;
    const int lane = t & 63;
    const int wave = t >> 6;             // 0..3 == B-staging ci
    const int wm   = (wave >> 1) * 64;
    const int wn   = (wave & 1) * 64;
    const int quad = lane >> 4;
    const int l16  = lane & 15;
    const int sw   = l16 & 7;            // A-read chunk XOR key
    const int o0 = m * BM;
    const int n0 = n * BN;
    const int nb0 = n * 4;               // first batch of this tile

    f32x4 acc[4][4] = {};

    // A staging: slot (row=32c+rA, chunk c8) holds global chunk c8^(rA&7)
    const int rA = t >> 3;               // 0..31
    const int c8 = t & 7;
    const int csw = (c8 ^ (rA & 7)) * 8;
    const u16* gA = Ab + (size_t)(o0 + rA) * astride + kb + csw;
    u16* lA = As + t * 8;

    for (int it = 0; it < kiters; ++it) {
        const int k0 = it * BK;
        #pragma unroll
        for (int c = 0; c < 4; ++c)
            load_lds_16B(gA + (size_t)(c * 32) * astride + k0, lA + c * 2048);

        // B staging: this wave's i' for the iter; 4 chunks (bloc 0..3)
        const int ip = ((kb + k0) >> 4) + wave;
        int rows[4], qp;
        if (isPos) {
            const int nl = ip >> 5, tt = (ip >> 1) & 15;
            qp = ip & 1;
            #pragma unroll
            for (int bl = 0; bl < 4; ++bl)
                rows[bl] = idx[((nb0 + bl) * 16 + nl) * TK + tt];
        } else {
            qp = ip & 1;
            const int r0 = ip >> 1;
            #pragma unroll
            for (int bl = 0; bl < 4; ++bl)
                rows[bl] = (nb0 + bl) * 16 + r0;
        }
        #pragma unroll
        for (int bl = 0; bl < 4; ++bl)
            load_lds_16B(f1t + ((size_t)rows[bl] * 2 + qp) * 512 + lane * 8,
                         Bs + (wave * 4 + bl) * 512);
        __syncthreads();

        #pragma unroll
        for (int ks = 0; ks < 2; ++ks) {
            bf16x8 af[4], bfr[4];
            #pragma unroll
            for (int mt = 0; mt < 4; ++mt) {
                u16x8 bits = *(const u16x8*)(As + (wm + mt * 16 + l16) * BK
                                                + (((ks * 4 + quad) ^ sw) * 8));
                af[mt] = __builtin_bit_cast(bf16x8, bits);
            }
            const int ci2 = ks * 2 + (quad >> 1);
            const int qh  = quad & 1;
            #pragma unroll
            for (int nt = 0; nt < 4; ++nt) {
                const int nn = wn + nt * 16 + l16;
                const int blocf = nn >> 5, w = nn & 31;
                u16x8 bits = *(const u16x8*)(Bs + (ci2 * 4 + blocf) * 512 + w * 16
                                                + ((qh ^ ((w >> 2) & 1)) * 8));
                bfr[nt] = __builtin_bit_cast(bf16x8, bits);
            }
            #pragma unroll
            for (int mt = 0; mt < 4; ++mt)
                #pragma unroll
                for (int nt = 0; nt < 4; ++nt)
                    acc[mt][nt] = __builtin_amdgcn_mfma_f32_16x16x32_bf16(
                        af[mt], bfr[nt], acc[mt][nt], 0, 0, 0);
        }
        __syncthreads();
    }

    // epilogue: C/D row=quad*4+reg, col=l16; atomic-accumulate at final
    // scattered position: out[(b*16+(o>>6))*2048 + (o&63)*32 + w]
    #pragma unroll
    for (int nt = 0; nt < 4; ++nt) {
        const int nn = n0 + wn + nt * 16 + l16;
        const int bb = nn >> 5, w = nn & 31;
        #pragma unroll
        for (int mt = 0; mt < 4; ++mt) {
            #pragma unroll
            for (int r = 0; r < 4; ++r) {
                const int o = o0 + wm + mt * 16 + quad * 4 + r;
                unsafeAtomicAdd(out + (size_t)(bb * 16 + (o >> 6)) * 2048
                                    + (o & 63) * 32 + w,
                                acc[mt][nt][r]);
            }
        }
    }
}

// ---------------------------------------------------------------------------
// Kernel 3: in-place bias + relu on the accumulated output.
// ---------------------------------------------------------------------------
__global__ __launch_bounds__(256) void finalize_kernel(float* __restrict__ out,
                                                       const float* __restrict__ bias) {
    const int tid = blockIdx.x * 256 + threadIdx.x;
    const int f = tid * 4;
    const int o = ((f >> 11) & 15) * 64 + ((f & 2047) >> 5);
    const float bv = bias[o];
    float4 x = *(float4*)(out + f);
    x.x = fmaxf(x.x + bv, 0.f);
    x.y = fmaxf(x.y + bv, 0.f);
    x.z = fmaxf(x.z + bv, 0.f);
    x.w = fmaxf(x.w + bv, 0.f);
    *(float4*)(out + f) = x;
}

// ---------------------------------------------------------------------------
extern "C" void kernel_launch(void* const* d_in, const int* in_sizes, int n_in,
                              void* d_out, int out_size, void* d_ws, size_t ws_size,
                              hipStream_t stream) {
    const float* f1   = (const float*)d_in[0];   // [1024][1024]
    const float* Wc   = (const float*)d_in[1];   // [1024][1024][16][1]
    const float* bias = (const float*)d_in[2];   // [1024]
    float* out = (float*)d_out;                  // [1024][2048]

    // workspace layout (bytes):
    //   idx:  0         (64KB)
    //   Wb:   65536     (1024*8192*2 = 16MB)
    //   W1b:  16842752  (1024*512*2  = 1MB)
    //   f1t:  17891328  (1024*2*512*2 = 2MB)
    int* idx = (int*)d_ws;
    u16* Wb  = (u16*)((char*)d_ws + 65536);
    u16* W1b = (u16*)((char*)d_ws + 16842752);
    u16* f1t = (u16*)((char*)d_ws + 17891328);

    prep_kernel<<<PREP_TOPK + PREP_ZERO + PREP_CONV + PREP_W1 + PREP_F1T,
                  256, 0, stream>>>(f1, Wc, idx, Wb, W1b, f1t, out);
    gemm_kernel<<<512 + 128, 256, 0, stream>>>(Wb, W1b, f1t, idx, out);
    finalize_kernel<<<(NDIM * NCOL) / (4 * 256), 256, 0, stream>>>(out, bias);
}

// Round 8
// 164.850 us; speedup vs baseline: 1.4339x; 1.0547x over previous
//
#include <hip/hip_runtime.h>
#include <stdint.h>

// y[b,o,w] = relu(bias[o] + sum_{i,kh} W[o,i,kh] * x[b,i,kh,w])
// q=i&3 split: q<2 ("rep") -> pre-sum W over tt => K=512 GEMM; q>=2 ("pos")
// keeps the gathered K=8192 GEMM, gather fused into GEMM staging from
// f1t[row][q][w][kh] bf16 (2MB, L2-resident).
// r8: K-loop restructured -- LDS double-buffer (A+B), ONE barrier/iter,
// idx slice preloaded to LDS. 3 dispatches: prep -> gemm -> finalize.

#define NDIM 1024
#define TK   16
#define KPOS 8192    // pos K: 512 i's * 16 kh
#define KREP 512     // rep K: 32 (nl,q) * 16 kh
#define NCOL 2048    // 64 batches * 32 width

typedef unsigned short u16;
typedef uint32_t u32;
typedef u16   u16x8  __attribute__((ext_vector_type(8)));
typedef __bf16 bf16x8 __attribute__((ext_vector_type(8)));
typedef float  f32x4  __attribute__((ext_vector_type(4)));

__device__ __forceinline__ u16 f2bf(float x) {
    union { float f; unsigned u; } v; v.f = x;
    unsigned r = 0x7FFFu + ((v.u >> 16) & 1u);   // round-to-nearest-even
    return (u16)((v.u + r) >> 16);
}

// async global->LDS, 16B/lane; LDS dest is wave-uniform base + lane*16
__device__ __forceinline__ void load_lds_16B(const u16* g, u16* l) {
    __builtin_amdgcn_global_load_lds(
        (__attribute__((address_space(1))) void*)(uintptr_t)g,
        (__attribute__((address_space(3))) void*)(unsigned)(uintptr_t)l,
        16, 0, 0);
}

// ---------------------------------------------------------------------------
// Kernel 1 (fused, grid-partitioned):
//   [0,256):      top-16 per row (wave/row, registers, exact fp32)
//   [256,2304):   zero d_out
//   [2304,6400):  conv_w pos half fp32 -> bf16 A_pos[o][k'], k'=i'*16+kh
//   [6400,7424):  W1[o][kr] = bf16(sum_tt W[o, nl*64+tt*4+q, kh]), q in {0,1}
//   [7424,7680):  f1t[row][q][w][kh^swp] = bf16(f1[row, q*512+kh*32+w]),
//                 swp = 8*((w>>2)&1)  (bank-spread half-swap for GEMM reads)
// ---------------------------------------------------------------------------
#define PREP_TOPK 256
#define PREP_ZERO 2048
#define PREP_CONV 4096
#define PREP_W1   1024
#define PREP_F1T  256

__global__ __launch_bounds__(256) void prep_kernel(const float* __restrict__ f1,
                                                   const float* __restrict__ W,
                                                   int* __restrict__ idx,
                                                   u16* __restrict__ Wb,
                                                   u16* __restrict__ W1b,
                                                   u16* __restrict__ f1t,
                                                   float* __restrict__ out) {
    const int bid = blockIdx.x;
    const int t = threadIdx.x;
    if (bid < PREP_TOPK) {
        // ---- top-16 ----
        const int lane = t & 63;
        const int row  = bid * 4 + (t >> 6);
        float v[16];
        const float* src = f1 + row * NDIM + lane;
        #pragma unroll
        for (int j = 0; j < 16; ++j) v[j] = src[j * 64];
        for (int sel = 0; sel < TK; ++sel) {
            float best = -3.402823466e38f; int bg = 0x7fffffff;
            #pragma unroll
            for (int j = 0; j < 16; ++j)
                if (v[j] > best) { best = v[j]; bg = j * 64 + lane; }
            #pragma unroll
            for (int s = 1; s < 64; s <<= 1) {
                float ov = __shfl_xor(best, s);
                int   og = __shfl_xor(bg, s);
                if (ov > best || (ov == best && og < bg)) { best = ov; bg = og; }
            }
            if (lane == sel) idx[row * TK + sel] = bg;
            #pragma unroll
            for (int j = 0; j < 16; ++j)
                if (bg == j * 64 + lane) v[j] = -3.402823466e38f;
        }
    } else if (bid < PREP_TOPK + PREP_ZERO) {
        // ---- zero the 8MB output accumulator ----
        const int zb = bid - PREP_TOPK;
        f32x4 z = {0.f, 0.f, 0.f, 0.f};
        *(f32x4*)(out + (size_t)(zb * 256 + t) * 4) = z;
    } else if (bid < PREP_TOPK + PREP_ZERO + PREP_CONV) {
        // ---- conv_w pos half -> bf16: i' = nl*32+tt*2+qp, i = nl*64+tt*4+qp+2
        const int tid = (bid - PREP_TOPK - PREP_ZERO) * 256 + t;  // < 1048576
        const int o  = tid >> 10;
        const int r  = tid & 1023;
        const int kp0 = r * 8;                 // k' base (8 consecutive)
        const int ip  = r >> 1;                // i'
        const int kh0 = (r & 1) * 8;
        const int i = (ip >> 5) * 64 + ((ip >> 1) & 15) * 4 + (ip & 1) + 2;
        const float* src = W + (size_t)o * 16384 + i * 16 + kh0;
        float4 a = *(const float4*)(src);
        float4 b = *(const float4*)(src + 4);
        u16x8 ov;
        ov[0] = f2bf(a.x); ov[1] = f2bf(a.y); ov[2] = f2bf(a.z); ov[3] = f2bf(a.w);
        ov[4] = f2bf(b.x); ov[5] = f2bf(b.y); ov[6] = f2bf(b.z); ov[7] = f2bf(b.w);
        *(u16x8*)(Wb + (size_t)o * KPOS + kp0) = ov;
    } else if (bid < PREP_TOPK + PREP_ZERO + PREP_CONV + PREP_W1) {
        // ---- W1 reduction over tt (rep half) ----
        const int o = bid - PREP_TOPK - PREP_ZERO - PREP_CONV;   // 0..1023
        const float* wrow = W + (size_t)o * 16384;
        #pragma unroll
        for (int h = 0; h < 2; ++h) {
            const int kr = h * 256 + t;        // 0..511
            const int nl = kr >> 5, q = (kr >> 4) & 1, kh = kr & 15;
            const float* base = wrow + (nl * 64 + q) * 16 + kh;
            float s = 0.f;
            #pragma unroll
            for (int tt = 0; tt < 16; ++tt) s += base[tt * 64];
            W1b[o * KREP + kr] = f2bf(s);
        }
    } else {
        // ---- f1 -> f1t bf16 transpose (w-major, kh half-swapped by w>>2&1) ----
        const int gb = bid - PREP_TOPK - PREP_ZERO - PREP_CONV - PREP_W1; // 0..255
        const int unit = t >> 5;               // 0..7
        const int w = t & 31;
        const int rq = gb * 8 + unit;          // 0..2047
        const int row = rq >> 1, q = rq & 1;
        const float* src = f1 + row * NDIM + q * 512;
        const int swp = ((w >> 2) & 1) * 8;
        u16 tmp[16];
        #pragma unroll
        for (int kh = 0; kh < 16; ++kh)
            tmp[kh ^ swp] = f2bf(src[kh * 32 + w]);   // coalesced per-kh across lanes
        u16* dst = f1t + ((size_t)row * 2 + q) * 512 + w * 16;
        *(u16x8*)(dst)     = *(u16x8*)(tmp);
        *(u16x8*)(dst + 8) = *(u16x8*)(tmp + 8);
    }
}

// ---------------------------------------------------------------------------
// Kernel 2: bf16 MFMA GEMM, 128x128 tile, BK=64, B gathered inline from f1t.
//   f < 512:  pos GEMM K=8192, split-K=4 (f=m*64+u, u=(n,z); XCD = u%8)
//   f >= 512: rep GEMM K=512 (128 blocks)
// r8 K-loop: LDS double-buffer A+B, ONE barrier per iter — at iter it, issue
// DMA for it+1 into buf[1-cur] then compute buf[cur]; the vmcnt(0) before
// the barrier drains loads that had the whole compute phase in flight.
// idx slice (256 ints) preloaded to LDS at start. Atomic scatter epilogue.
// ---------------------------------------------------------------------------
#define BM 128
#define BN 128
#define BK 64

__global__ __launch_bounds__(256, 2) void gemm_kernel(const u16* __restrict__ Ap,
                                                      const u16* __restrict__ A1,
                                                      const u16* __restrict__ f1t,
                                                      const int* __restrict__ idx,
                                                      float* __restrict__ out) {
    __shared__ __align__(16) u16 As[2][BM * BK];   // 2x16KB, [row][chunk^(row&7)]
    __shared__ __align__(16) u16 Bs[2][16 * 512];  // 2x16KB, [ci][bloc][w][half]
    __shared__ int idxL[256];                       // [bl][nlz][tt]
    const int f = blockIdx.x;            // 0..639
    int m, n, kb, kiters, astride;
    const u16* Ab;
    bool isPos;
    if (f < 512) {
        m = f >> 6; const int u = f & 63; n = u & 15;
        astride = KPOS; kb = (u >> 4) * 2048; kiters = 32; Ab = Ap; isPos = true;
    } else {
        const int g = f - 512; m = g >> 4; n = g & 15;
        astride = KREP; kb = 0; kiters = 8; Ab = A1; isPos = false;
    }
    const int t    = threadIdx.x;
    const int lane = t & 63;
    const int wave = t >> 6;             // 0..3 == B-staging ci
    const int wm   = (wave >> 1) * 64;
    const int wn   = (wave & 1) * 64;
    const int quad = lane >> 4;
    const int l16  = lane & 15;
    const int sw   = l16 & 7;            // A-read chunk XOR key
    const int o0 = m * BM;
    const int n0 = n * BN;
    const int nb0 = n * 4;               // first batch of this tile
    const int nl0 = kb >> 9;             // z*4

    // preload this block's idx slice: idxL[bl*64 + nlz*16 + tt]
    if (isPos) {
        const int bl = t >> 6, nlz = (t >> 4) & 3, tt = t & 15;
        idxL[t] = idx[((nb0 + bl) * 16 + nl0 + nlz) * TK + tt];
    }

    f32x4 acc[4][4] = {};

    // A staging addresses: slot (row=32c+rA, chunk c8) holds chunk c8^(rA&7)
    const int rA = t >> 3;               // 0..31
    const int c8 = t & 7;
    const int csw = (c8 ^ (rA & 7)) * 8;
    const u16* gA = Ab + (size_t)(o0 + rA) * astride + kb + csw;
    const int ipb = kb >> 4;             // ip base

    // stage iteration `it` into buffer `nb`
    auto stage = [&](int it, int nb) {
        const int k0 = it * BK;
        u16* lA = As[nb] + t * 8;
        #pragma unroll
        for (int c = 0; c < 4; ++c)
            load_lds_16B(gA + (size_t)(c * 32) * astride + k0, lA + c * 2048);
        const int ip = ipb + it * 4 + wave;
        const int qp = ip & 1;
        int rows[4];
        if (isPos) {
            const int nlz = (ip >> 5) & 3, tt = (ip >> 1) & 15;
            #pragma unroll
            for (int bl = 0; bl < 4; ++bl)
                rows[bl] = idxL[bl * 64 + nlz * 16 + tt];
        } else {
            const int r0 = ip >> 1;
            #pragma unroll
            for (int bl = 0; bl < 4; ++bl)
                rows[bl] = (nb0 + bl) * 16 + r0;
        }
        #pragma unroll
        for (int bl = 0; bl < 4; ++bl)
            load_lds_16B(f1t + ((size_t)rows[bl] * 2 + qp) * 512 + lane * 8,
                         Bs[nb] + (wave * 4 + bl) * 512);
    };

    __syncthreads();        // idxL visible before first stage reads it
    stage(0, 0);
    __syncthreads();        // drain prologue DMA

    #pragma unroll 2
    for (int it = 0; it < kiters; ++it) {
        const int cur = it & 1;
        if (it + 1 < kiters) stage(it + 1, 1 - cur);

        #pragma unroll
        for (int ks = 0; ks < 2; ++ks) {
            bf16x8 af[4], bfr[4];
            #pragma unroll
            for (int mt = 0; mt < 4; ++mt) {
                u16x8 bits = *(const u16x8*)(As[cur] + (wm + mt * 16 + l16) * BK
                                                + (((ks * 4 + quad) ^ sw) * 8));
                af[mt] = __builtin_bit_cast(bf16x8, bits);
            }
            const int ci2 = ks * 2 + (quad >> 1);
            const int qh  = quad & 1;
            #pragma unroll
            for (int nt = 0; nt < 4; ++nt) {
                const int nn = wn + nt * 16 + l16;
                const int blocf = nn >> 5, w = nn & 31;
                u16x8 bits = *(const u16x8*)(Bs[cur] + (ci2 * 4 + blocf) * 512 + w * 16
                                                + ((qh ^ ((w >> 2) & 1)) * 8));
                bfr[nt] = __builtin_bit_cast(bf16x8, bits);
            }
            #pragma unroll
            for (int mt = 0; mt < 4; ++mt)
                #pragma unroll
                for (int nt = 0; nt < 4; ++nt)
                    acc[mt][nt] = __builtin_amdgcn_mfma_f32_16x16x32_bf16(
                        af[mt], bfr[nt], acc[mt][nt], 0, 0, 0);
        }
        __syncthreads();    // one barrier per iter: releases buf[cur] for
                            // rewrite AND drains the it+1 DMAs (vmcnt(0))
    }

    // epilogue: C/D row=quad*4+reg, col=l16; atomic-accumulate at final
    // scattered position: out[(b*16+(o>>6))*2048 + (o&63)*32 + w]
    #pragma unroll
    for (int nt = 0; nt < 4; ++nt) {
        const int nn = n0 + wn + nt * 16 + l16;
        const int bb = nn >> 5, w = nn & 31;
        #pragma unroll
        for (int mt = 0; mt < 4; ++mt) {
            #pragma unroll
            for (int r = 0; r < 4; ++r) {
                const int o = o0 + wm + mt * 16 + quad * 4 + r;
                unsafeAtomicAdd(out + (size_t)(bb * 16 + (o >> 6)) * 2048
                                    + (o & 63) * 32 + w,
                                acc[mt][nt][r]);
            }
        }
    }
}

// ---------------------------------------------------------------------------
// Kernel 3: in-place bias + relu on the accumulated output.
// ---------------------------------------------------------------------------
__global__ __launch_bounds__(256) void finalize_kernel(float* __restrict__ out,
                                                       const float* __restrict__ bias) {
    const int tid = blockIdx.x * 256 + threadIdx.x;
    const int f = tid * 4;
    const int o = ((f >> 11) & 15) * 64 + ((f & 2047) >> 5);
    const float bv = bias[o];
    float4 x = *(float4*)(out + f);
    x.x = fmaxf(x.x + bv, 0.f);
    x.y = fmaxf(x.y + bv, 0.f);
    x.z = fmaxf(x.z + bv, 0.f);
    x.w = fmaxf(x.w + bv, 0.f);
    *(float4*)(out + f) = x;
}

// ---------------------------------------------------------------------------
extern "C" void kernel_launch(void* const* d_in, const int* in_sizes, int n_in,
                              void* d_out, int out_size, void* d_ws, size_t ws_size,
                              hipStream_t stream) {
    const float* f1   = (const float*)d_in[0];   // [1024][1024]
    const float* Wc   = (const float*)d_in[1];   // [1024][1024][16][1]
    const float* bias = (const float*)d_in[2];   // [1024]
    float* out = (float*)d_out;                  // [1024][2048]

    // workspace layout (bytes):
    //   idx:  0         (64KB)
    //   Wb:   65536     (1024*8192*2 = 16MB)
    //   W1b:  16842752  (1024*512*2  = 1MB)
    //   f1t:  17891328  (1024*2*512*2 = 2MB)
    int* idx = (int*)d_ws;
    u16* Wb  = (u16*)((char*)d_ws + 65536);
    u16* W1b = (u16*)((char*)d_ws + 16842752);
    u16* f1t = (u16*)((char*)d_ws + 17891328);

    prep_kernel<<<PREP_TOPK + PREP_ZERO + PREP_CONV + PREP_W1 + PREP_F1T,
                  256, 0, stream>>>(f1, Wc, idx, Wb, W1b, f1t, out);
    gemm_kernel<<<512 + 128, 256, 0, stream>>>(Wb, W1b, f1t, idx, out);
    finalize_kernel<<<(NDIM * NCOL) / (4 * 256), 256, 0, stream>>>(out, bias);
}